// Round 9
// baseline (536.866 us; speedup 1.0000x reference)
//
#include <hip/hip_runtime.h>
#include <hip/hip_bf16.h>

// Problem constants (shapes fixed by reference; N's derived from in_sizes)
#define R_SUP 5
#define D_IN 128
#define O_OUT 64
#define NBMAX 512          // max coarse buckets
#define CHUNK 8192         // edges per workgroup in coarse_scatter
#define FCAP 4608          // LDS window (input entries) per sort chunk

typedef __attribute__((ext_vector_type(8))) short bf16x8;
typedef __attribute__((ext_vector_type(4))) float f32x4;

// fp32 -> bf16 round-to-nearest-even
__device__ __forceinline__ unsigned short f2bf(float f) {
  union { float f; unsigned int u; } c; c.f = f;
  unsigned int u = c.u;
  return (unsigned short)((u + 0x7FFFu + ((u >> 16) & 1u)) >> 16);
}
__device__ __forceinline__ float bf2f(unsigned short h) {
  return __uint_as_float(((unsigned int)h) << 16);
}

// ---------------------------------------------------------------------------
// cumsum over relation axis; emits fp32 cumsum (fallback path) AND transposed
// bf16 weights wtb[r][o][k] for the MFMA path. i indexes (d,o), o fastest.
__global__ __launch_bounds__(256) void cumsum_w(
    const float* __restrict__ wu, const float* __restrict__ wv,
    float* __restrict__ wcu, float* __restrict__ wcv,
    unsigned short* __restrict__ wtbu, unsigned short* __restrict__ wtbv) {
  int i = blockIdx.x * 256 + threadIdx.x;
  if (i >= D_IN * O_OUT) return;
  const int d = i >> 6;
  const int o = i & 63;
  float su = 0.f, sv = 0.f;
#pragma unroll
  for (int r = 0; r < R_SUP; ++r) {
    su += wu[r * D_IN * O_OUT + i];
    sv += wv[r * D_IN * O_OUT + i];
    wcu[r * D_IN * O_OUT + i] = su;
    wcv[r * D_IN * O_OUT + i] = sv;
    wtbu[((size_t)r * O_OUT + o) * D_IN + d] = f2bf(su);
    wtbv[((size_t)r * O_OUT + o) * D_IN + d] = f2bf(sv);
  }
}

__global__ __launch_bounds__(256) void zero_f32(float* __restrict__ p, int n4) {
  int i = blockIdx.x * 256 + threadIdx.x;
  int stride = gridDim.x * 256;
  float4 z = make_float4(0.f, 0.f, 0.f, 0.f);
  for (; i < n4; i += stride) ((float4*)p)[i] = z;
}

__global__ __launch_bounds__(256) void zero_i32(int* __restrict__ p, int n) {
  int i = blockIdx.x * 256 + threadIdx.x;
  int stride = gridDim.x * 256;
  for (; i < n; i += stride) p[i] = 0;
}

// ---------------------------------------------------------------------------
// MFMA batched GEMM: tmp5[r][n][o] = bf16( sum_d x[n][d] * W[r][d][o] )
// x: [N][128] fp32 (conversion fused).  wtb: [5][64][128] bf16.
// Output staged through LDS so the 8KB tile store is fully coalesced.
__global__ __launch_bounds__(256) void gemm5_mfma(
    const float* __restrict__ x,
    const unsigned short* __restrict__ wtb,
    unsigned short* __restrict__ tmp5, size_t strideR, int N) {
  __shared__ unsigned short st[64][72];  // pad 72: 16B-aligned rows, 18KB
  const int tid = threadIdx.x;
  const int row0 = blockIdx.x * 64;
  const int wave = tid >> 6;
  const int lane = tid & 63;
  const int m = lane & 15;
  const int q = lane >> 4;
  const int o0 = wave * 16;

  bf16x8 a[4][4];
#pragma unroll
  for (int rt = 0; rt < 4; ++rt) {
    int row = row0 + rt * 16 + m;
    if (row >= N) row = N - 1;  // clamp: loads harmless, stores guarded
    const float* px = x + (size_t)row * D_IN + q * 8;
#pragma unroll
    for (int k0 = 0; k0 < 4; ++k0) {
      float4 f0 = *(const float4*)(px + k0 * 32);
      float4 f1 = *(const float4*)(px + k0 * 32 + 4);
      bf16x8 t;
      t[0] = (short)f2bf(f0.x); t[1] = (short)f2bf(f0.y);
      t[2] = (short)f2bf(f0.z); t[3] = (short)f2bf(f0.w);
      t[4] = (short)f2bf(f1.x); t[5] = (short)f2bf(f1.y);
      t[6] = (short)f2bf(f1.z); t[7] = (short)f2bf(f1.w);
      a[rt][k0] = t;
    }
  }

  const int rr = tid >> 2;          // writeout row 0..63
  const int c0 = (tid & 3) * 16;    // writeout col chunk

  for (int r = 0; r < R_SUP; ++r) {
    bf16x8 b[4];
    const unsigned short* pw =
        wtb + ((size_t)r * O_OUT + o0 + m) * D_IN + q * 8;
#pragma unroll
    for (int k0 = 0; k0 < 4; ++k0)
      b[k0] = *(const bf16x8*)(pw + k0 * 32);
#pragma unroll
    for (int rt = 0; rt < 4; ++rt) {
      f32x4 acc = {0.f, 0.f, 0.f, 0.f};
#pragma unroll
      for (int k0 = 0; k0 < 4; ++k0)
        acc = __builtin_amdgcn_mfma_f32_16x16x32_bf16(a[rt][k0], b[k0], acc,
                                                      0, 0, 0);
#pragma unroll
      for (int reg = 0; reg < 4; ++reg)
        st[rt * 16 + q * 4 + reg][o0 + m] = f2bf(acc[reg]);
    }
    __syncthreads();
    // coalesced tile store: 256 threads x 32B cover the 8KB contiguous tile
    if (row0 + rr < N) {
      unsigned short* pz = tmp5 + (size_t)r * strideR + (size_t)row0 * O_OUT;
      *(int4*)(pz + rr * O_OUT + c0) = *(const int4*)&st[rr][c0];
      *(int4*)(pz + rr * O_OUT + c0 + 8) = *(const int4*)&st[rr][c0 + 8];
    }
    __syncthreads();
  }
}

// ---------------------------------------------------------------------------
// Coarse bucket histogram, both directions, int4-vectorized edge loads.
__global__ __launch_bounds__(256) void coarse_hist(
    const int* __restrict__ rows, const int* __restrict__ cols,
    int* __restrict__ cnt_u, int* __restrict__ cnt_v, int nE5,
    int nbu, int nbv) {
  __shared__ int hu[NBMAX], hv[NBMAX];
  const int tid = threadIdx.x;
  for (int t = tid; t < NBMAX; t += 256) { hu[t] = 0; hv[t] = 0; }
  __syncthreads();
  const int n4 = nE5 >> 2;
  int i = blockIdx.x * 256 + tid;
  int stride = gridDim.x * 256;
  for (; i < n4; i += stride) {
    int4 rr = ((const int4*)rows)[i];
    int4 cc = ((const int4*)cols)[i];
    atomicAdd(&hu[rr.x >> 8], 1); atomicAdd(&hu[rr.y >> 8], 1);
    atomicAdd(&hu[rr.z >> 8], 1); atomicAdd(&hu[rr.w >> 8], 1);
    atomicAdd(&hv[cc.x >> 8], 1); atomicAdd(&hv[cc.y >> 8], 1);
    atomicAdd(&hv[cc.z >> 8], 1); atomicAdd(&hv[cc.w >> 8], 1);
  }
  // tail
  for (i = (n4 << 2) + blockIdx.x * 256 + tid; i < nE5; i += stride) {
    atomicAdd(&hu[rows[i] >> 8], 1);
    atomicAdd(&hv[cols[i] >> 8], 1);
  }
  __syncthreads();
  for (int t = tid; t < nbu; t += 256) if (hu[t]) atomicAdd(&cnt_u[t], hu[t]);
  for (int t = tid; t < nbv; t += 256) if (hv[t]) atomicAdd(&cnt_v[t], hv[t]);
}

// Exclusive scan over coarse buckets. grid=2 (0->u, 1->v).
__global__ __launch_bounds__(512) void coarse_scan(
    int* __restrict__ cnt_u, int* __restrict__ cnt_v,
    int* __restrict__ cb_u, int* __restrict__ cb_v,
    int* __restrict__ gcur_u, int* __restrict__ gcur_v, int nbu, int nbv) {
  int* cnt = blockIdx.x ? cnt_v : cnt_u;
  int* cb  = blockIdx.x ? cb_v  : cb_u;
  int* gc  = blockIdx.x ? gcur_v : gcur_u;
  int nb   = blockIdx.x ? nbv   : nbu;
  __shared__ int sc[NBMAX];
  const int t = threadIdx.x;
  sc[t] = (t < nb) ? cnt[t] : 0;
  __syncthreads();
  for (int off = 1; off < NBMAX; off <<= 1) {
    int add = (t >= off) ? sc[t - off] : 0;
    __syncthreads();
    sc[t] += add;
    __syncthreads();
  }
  int excl = t ? sc[t - 1] : 0;
  if (t < nb) { cb[t] = excl; gc[t] = excl; }
  if (t == 0) cb[nb] = sc[NBMAX - 1];
}

// ---------------------------------------------------------------------------
// Coarse scatter, LDS-staged + bucket-sorted + coalesced run flush.
// One direction per block (blockIdx.x & 1). CHUNK=8192 (known-good config).
// payload: x = dst_lo<<20 | r<<17 | src, y = val bits
__global__ __launch_bounds__(512) void coarse_scatter(
    const int* __restrict__ rows, const int* __restrict__ cols,
    const float* __restrict__ vals, int* __restrict__ gcur_u,
    int* __restrict__ gcur_v, int2* __restrict__ mid_u,
    int2* __restrict__ mid_v, int nE5, int E, int nbu, int nbv) {
  __shared__ int2 buf[CHUNK];            // 64 KB
  __shared__ int h[NBMAX], sc[NBMAX], gb[NBMAX], cur[NBMAX];  // 8 KB
  const int tid = threadIdx.x;
  const int dir = blockIdx.x & 1;
  const int base = (blockIdx.x >> 1) * CHUNK;
  const int end = min(base + CHUNK, nE5);
  const int E2 = 2 * E, E3 = 3 * E, E4 = 4 * E;

  const int* ids   = dir ? cols : rows;
  const int* other = dir ? rows : cols;
  int* gcur = dir ? gcur_v : gcur_u;
  int2* mid = dir ? mid_v : mid_u;
  const int nb = dir ? nbv : nbu;

  h[tid] = 0;                // tid < 512 == NBMAX
  __syncthreads();
  // 1. histogram of this chunk
  for (int i = base + tid; i < end; i += 512)
    atomicAdd(&h[ids[i] >> 8], 1);
  __syncthreads();
  // 2. inclusive scan (Hillis-Steele, 512 threads == NBMAX elems)
  sc[tid] = h[tid];
  __syncthreads();
  for (int off = 1; off < NBMAX; off <<= 1) {
    int add = (tid >= off) ? sc[tid - off] : 0;
    __syncthreads();
    sc[tid] += add;
    __syncthreads();
  }
  // 3. reserve global runs; init local cursors to exclusive scan
  int excl = tid ? sc[tid - 1] : 0;
  cur[tid] = excl;
  if (tid < nb && h[tid]) gb[tid] = atomicAdd(&gcur[tid], h[tid]);
  __syncthreads();
  // 4. place payloads into LDS, bucket-sorted
  for (int i = base + tid; i < end; i += 512) {
    int id = ids[i];
    int src = other[i];
    int vb = __float_as_int(vals[i]);
    int r = (i >= E) + (i >= E2) + (i >= E3) + (i >= E4);
    int pos = atomicAdd(&cur[id >> 8], 1);
    buf[pos] = make_int2(((id & 255) << 20) | (r << 17) | src, vb);
  }
  __syncthreads();
  // 5. flush runs: wave w handles buckets w, w+8, ...; lanes consecutive
  const int wv = tid >> 6;
  const int lane = tid & 63;
  for (int b = wv; b < nb; b += 8) {
    int s = b ? sc[b - 1] : 0;
    int e = sc[b];
    if (s == e) continue;
    int2* dst = mid + gb[b];
    for (int j = s + lane; j < e; j += 64) dst[j - s] = buf[j];
  }
}

// ---------------------------------------------------------------------------
// Fused fine-sort + pull SpMM + ReLU, dst-range SPLIT over 2 blocks/bucket.
// grid = 2*nbuck; block (b, part) owns dls [part*128, part*128+128).
// Round-8 lesson: occupancy was block-SUPPLY-limited (grid nbuck=391 ~1.5
// blk/CU), not LDS-limited. Splitting the dst range doubles the grid; with
// 37.9KB LDS (4 blk/CU capacity) all 782 blocks are co-resident, so sort
// phases overlap sibling gather phases. Each block reads the full bucket
// edge list but filters to its half (mid read x2 = +25.6MB/dir, stream-cheap).
// Accumulation stays in REGISTERS. mid entry: x = dst_lo<<20 | r<<17 | src.
__global__ __launch_bounds__(512) void spmm_sorted(
    const int2* __restrict__ mid, const int* __restrict__ cb,
    const unsigned short* __restrict__ tmp5, float* __restrict__ z,
    int Ndst, int strideR) {
  __shared__ int2 buf[FCAP];           // 36864 B
  __shared__ int sc[128], cur[128];    // 1 KB
  const int tid = threadIdx.x;
  const int b = blockIdx.x >> 1;
  const int part = blockIdx.x & 1;
  const int s = cb[b];
  const int e = cb[b + 1];
  const int d0 = b * 256 + part * 128;
  const int gid = tid >> 4;     // 32 groups of 16 lanes
  const int lane = tid & 15;
  const unsigned short* tl = tmp5 + lane * 4;  // per-lane 8B slice

  float4 acc[4];
#pragma unroll
  for (int k = 0; k < 4; ++k) acc[k] = make_float4(0.f, 0.f, 0.f, 0.f);

  for (int cs = s; cs < e; cs += FCAP) {
    const int ce = min(cs + FCAP, e);
    if (tid < 128) sc[tid] = 0;
    __syncthreads();
    // hist over this window, filtered to our dl half
    for (int i = cs + tid; i < ce; i += 512) {
      int dl = (mid[i].x >> 20) & 255;
      if ((dl >> 7) == part) atomicAdd(&sc[dl & 127], 1);
    }
    __syncthreads();
    // inclusive scan of 128 counters
    for (int off = 1; off < 128; off <<= 1) {
      int add = (tid < 128 && tid >= off) ? sc[tid - off] : 0;
      __syncthreads();
      if (tid < 128) sc[tid] += add;
      __syncthreads();
    }
    if (tid < 128) cur[tid] = tid ? sc[tid - 1] : 0;
    __syncthreads();
    // place (filtered) sorted-by-dst into LDS; precompute tmp5 elem offset
    for (int i = cs + tid; i < ce; i += 512) {
      int2 pk = mid[i];
      int dl = (pk.x >> 20) & 255;
      if ((dl >> 7) != part) continue;
      int r = (pk.x >> 17) & 7;
      int src = pk.x & 0x1FFFF;
      int pos = atomicAdd(&cur[dl & 127], 1);
      buf[pos] = make_int2(r * strideR + (src << 6), pk.y);
    }
    __syncthreads();
    // gather + register accumulate: group gid owns dls gid, gid+32, ...
#pragma unroll
    for (int k = 0; k < 4; ++k) {
      const int dl = gid + (k << 5);  // 0..127 within our half
      int i = dl ? sc[dl - 1] : 0;
      const int re = sc[dl];
      float4 a = acc[k];
      for (; i + 8 <= re; i += 8) {
        int2 pk[8];
#pragma unroll
        for (int j = 0; j < 8; ++j) pk[j] = buf[i + j];
        ushort4 hh[8];
#pragma unroll
        for (int j = 0; j < 8; ++j)
          hh[j] = *(const ushort4*)(tl + (unsigned)pk[j].x);
#pragma unroll
        for (int j = 0; j < 8; ++j) {
          float v = __int_as_float(pk[j].y);
          a.x += v * bf2f(hh[j].x);
          a.y += v * bf2f(hh[j].y);
          a.z += v * bf2f(hh[j].z);
          a.w += v * bf2f(hh[j].w);
        }
      }
      for (; i < re; ++i) {
        int2 pk = buf[i];
        float v = __int_as_float(pk.y);
        ushort4 hh = *(const ushort4*)(tl + (unsigned)pk.x);
        a.x += v * bf2f(hh.x);
        a.y += v * bf2f(hh.y);
        a.z += v * bf2f(hh.z);
        a.w += v * bf2f(hh.w);
      }
      acc[k] = a;
    }
    __syncthreads();  // protect buf/sc reuse next chunk
  }
  // ReLU + coalesced writeout
#pragma unroll
  for (int k = 0; k < 4; ++k) {
    int d = d0 + gid + (k << 5);
    if (d < Ndst) {
      float4 o;
      o.x = fmaxf(acc[k].x, 0.f);
      o.y = fmaxf(acc[k].y, 0.f);
      o.z = fmaxf(acc[k].z, 0.f);
      o.w = fmaxf(acc[k].w, 0.f);
      ((float4*)(z + (size_t)d * O_OUT))[lane] = o;
    }
  }
}

// ---------------------------------------------------------------------------
// Fallback (push-atomic) kernels — only used if ws_size is tiny.
__global__ __launch_bounds__(256) void gemm64(
    const float* __restrict__ x, const float* __restrict__ w,
    float* __restrict__ out, int N) {
  __shared__ float sXT[D_IN][68];
  __shared__ float sW[D_IN][O_OUT];
  const int tid = threadIdx.x;
  const int row0 = blockIdx.x * 64;
  for (int i = tid; i < 2048; i += 256) {
    int d = i >> 4;
    int o4 = i & 15;
    ((float4*)&sW[d][0])[o4] = ((const float4*)w)[i];
  }
  for (int i = tid; i < 2048; i += 256) {
    int rl = i >> 5;
    int d4 = i & 31;
    int row = row0 + rl;
    float4 xv = make_float4(0.f, 0.f, 0.f, 0.f);
    if (row < N) xv = ((const float4*)x)[(size_t)row * 32 + d4];
    sXT[d4 * 4 + 0][rl] = xv.x;
    sXT[d4 * 4 + 1][rl] = xv.y;
    sXT[d4 * 4 + 2][rl] = xv.z;
    sXT[d4 * 4 + 3][rl] = xv.w;
  }
  __syncthreads();
  const int col4 = (tid & 15) * 4;
  const int row4 = (tid >> 4) * 4;
  float acc[4][4] = {};
#pragma unroll 8
  for (int d = 0; d < D_IN; ++d) {
    float4 xv = *(const float4*)&sXT[d][row4];
    float4 wv = *(const float4*)&sW[d][col4];
    acc[0][0] += xv.x * wv.x; acc[0][1] += xv.x * wv.y; acc[0][2] += xv.x * wv.z; acc[0][3] += xv.x * wv.w;
    acc[1][0] += xv.y * wv.x; acc[1][1] += xv.y * wv.y; acc[1][2] += xv.y * wv.z; acc[1][3] += xv.y * wv.w;
    acc[2][0] += xv.z * wv.x; acc[2][1] += xv.z * wv.y; acc[2][2] += xv.z * wv.z; acc[2][3] += xv.z * wv.w;
    acc[3][0] += xv.w * wv.x; acc[3][1] += xv.w * wv.y; acc[3][2] += xv.w * wv.z; acc[3][3] += xv.w * wv.w;
  }
#pragma unroll
  for (int i = 0; i < 4; ++i) {
    int row = row0 + row4 + i;
    if (row < N)
      *(float4*)&out[row * O_OUT + col4] =
          make_float4(acc[i][0], acc[i][1], acc[i][2], acc[i][3]);
  }
}

__global__ __launch_bounds__(256) void spmm_push(
    const int* __restrict__ dst, const int* __restrict__ src,
    const float* __restrict__ vals, const float* __restrict__ tmp,
    float* __restrict__ z, int E) {
  int t = blockIdx.x * 256 + threadIdx.x;
  int e = t >> 4;
  int lane = t & 15;
  if (e >= E) return;
  int d_ = dst[e];
  int s_ = src[e];
  float v = vals[e];
  float4 f = ((const float4*)tmp)[s_ * 16 + lane];
  float* zp = z + (size_t)d_ * O_OUT + lane * 4;
  atomicAdd(zp + 0, v * f.x);
  atomicAdd(zp + 1, v * f.y);
  atomicAdd(zp + 2, v * f.z);
  atomicAdd(zp + 3, v * f.w);
}

__global__ __launch_bounds__(256) void relu_f32(float* __restrict__ p, int n4) {
  int i = blockIdx.x * 256 + threadIdx.x;
  int stride = gridDim.x * 256;
  for (; i < n4; i += stride) {
    float4 v = ((float4*)p)[i];
    v.x = v.x > 0.f ? v.x : 0.f;
    v.y = v.y > 0.f ? v.y : 0.f;
    v.z = v.z > 0.f ? v.z : 0.f;
    v.w = v.w > 0.f ? v.w : 0.f;
    ((float4*)p)[i] = v;
  }
}

// ---------------------------------------------------------------------------
extern "C" void kernel_launch(void* const* d_in, const int* in_sizes, int n_in,
                              void* d_out, int out_size, void* d_ws, size_t ws_size,
                              hipStream_t stream) {
  const float* x_u      = (const float*)d_in[0];
  const float* x_v      = (const float*)d_in[1];
  const int*   sup_rows = (const int*)d_in[2];
  const int*   sup_cols = (const int*)d_in[3];
  const float* sup_vals = (const float*)d_in[4];
  const float* wu       = (const float*)d_in[5];
  const float* wv       = (const float*)d_in[6];

  const int NU = in_sizes[0] / D_IN;
  const int NV = in_sizes[1] / D_IN;
  const int E  = in_sizes[2] / R_SUP;
  const int Nmax = NU > NV ? NU : NV;
  const int nE5 = R_SUP * E;
  const int nbu = (NU + 255) / 256;
  const int nbv = (NV + 255) / 256;
  const int nbmax = nbu > nbv ? nbu : nbv;

  float* out = (float*)d_out;
  float* z_u = out;
  float* z_v = out + (size_t)NU * O_OUT;

  const int WDO = R_SUP * D_IN * O_OUT;  // 40960
  const size_t strideR = (size_t)Nmax * O_OUT;
  const size_t bpad = (size_t)nbmax + 16;

  const size_t mid_bytes = (((size_t)nE5 * 8) + 255) & ~(size_t)255;

  // --- Radix path workspace layout (fin/rp eliminated) ---
  const size_t needR = 2 * mid_bytes + strideR * R_SUP * 2 +
                       (size_t)2 * WDO * 4 + (size_t)2 * WDO * 2 +
                       6 * bpad * 4 + 512;

  if (ws_size >= needR && nbmax <= NBMAX && Nmax < (1 << 17)) {
    char* base = (char*)d_ws;
    int2* mid_u = (int2*)base;
    int2* mid_v = (int2*)(base + mid_bytes);
    unsigned short* tmp5 = (unsigned short*)(base + 2 * mid_bytes);
    float* wcu = (float*)(tmp5 + strideR * R_SUP);
    float* wcv = wcu + WDO;
    unsigned short* wtbu = (unsigned short*)(wcv + WDO);
    unsigned short* wtbv = wtbu + WDO;
    int* cnt_u = (int*)(wtbv + WDO);
    int* cnt_v = cnt_u + bpad;
    int* cb_u  = cnt_v + bpad;
    int* cb_v  = cb_u + bpad;
    int* gcur_u = cb_v + bpad;
    int* gcur_v = gcur_u + bpad;

    cumsum_w<<<(D_IN * O_OUT + 255) / 256, 256, 0, stream>>>(
        wu, wv, wcu, wcv, wtbu, wtbv);
    zero_i32<<<(2 * (int)bpad + 255) / 256, 256, 0, stream>>>(cnt_u, 2 * (int)bpad);
    coarse_hist<<<512, 256, 0, stream>>>(sup_rows, sup_cols, cnt_u, cnt_v,
                                         nE5, nbu, nbv);
    coarse_scan<<<2, 512, 0, stream>>>(cnt_u, cnt_v, cb_u, cb_v, gcur_u,
                                       gcur_v, nbu, nbv);
    coarse_scatter<<<2 * ((nE5 + CHUNK - 1) / CHUNK), 512, 0, stream>>>(
        sup_rows, sup_cols, sup_vals, gcur_u, gcur_v, mid_u, mid_v, nE5, E,
        nbu, nbv);

    // ---- direction u: z_u = relu(sum_r S_r @ (x_v @ Wv_cum[r])) ----
    gemm5_mfma<<<(NV + 63) / 64, 256, 0, stream>>>(x_v, wtbv, tmp5, strideR, NV);
    spmm_sorted<<<2 * nbu, 512, 0, stream>>>(mid_u, cb_u, tmp5, z_u, NU,
                                             (int)strideR);

    // ---- direction v: z_v = relu(sum_r S_r^T @ (x_u @ Wu_cum[r])) ----
    gemm5_mfma<<<(NU + 63) / 64, 256, 0, stream>>>(x_u, wtbu, tmp5, strideR, NU);
    spmm_sorted<<<2 * nbv, 512, 0, stream>>>(mid_v, cb_v, tmp5, z_v, NV,
                                             (int)strideR);
  } else {
    // ---- fallback: push-atomic path ----
    float* wcu = (float*)d_ws;
    float* wcv = wcu + WDO;
    unsigned short* wtbu = (unsigned short*)(wcv + WDO);
    unsigned short* wtbv = wtbu + WDO;
    float* tmp = (float*)(wtbv + WDO);
    const int n4_out = out_size / 4;
    cumsum_w<<<(D_IN * O_OUT + 255) / 256, 256, 0, stream>>>(
        wu, wv, wcu, wcv, wtbu, wtbv);
    zero_f32<<<1024, 256, 0, stream>>>(out, n4_out);
    const int spmm_blocks = (E * 16 + 255) / 256;
    for (int r = 0; r < R_SUP; ++r) {
      const int* rws = sup_rows + (size_t)r * E;
      const int* cls = sup_cols + (size_t)r * E;
      const float* vls = sup_vals + (size_t)r * E;
      gemm64<<<(NV + 63) / 64, 256, 0, stream>>>(x_v, wcv + r * D_IN * O_OUT, tmp, NV);
      spmm_push<<<spmm_blocks, 256, 0, stream>>>(rws, cls, vls, tmp, z_u, E);
      gemm64<<<(NU + 63) / 64, 256, 0, stream>>>(x_u, wcu + r * D_IN * O_OUT, tmp, NU);
      spmm_push<<<spmm_blocks, 256, 0, stream>>>(cls, rws, vls, tmp, z_v, E);
    }
    relu_f32<<<1024, 256, 0, stream>>>(out, n4_out);
  }
}

// Round 10
// 501.145 us; speedup vs baseline: 1.0713x; 1.0713x over previous
//
#include <hip/hip_runtime.h>
#include <hip/hip_bf16.h>

// Problem constants (shapes fixed by reference; N's derived from in_sizes)
#define R_SUP 5
#define D_IN 128
#define O_OUT 64
#define NBMAX 512          // max coarse buckets
#define CHUNK 8192         // edges per workgroup in coarse_scatter
#define FCAP 9216          // LDS-staged sorted entries per chunk (72 KB)

typedef __attribute__((ext_vector_type(8))) short bf16x8;
typedef __attribute__((ext_vector_type(4))) float f32x4;

// fp32 -> bf16 round-to-nearest-even
__device__ __forceinline__ unsigned short f2bf(float f) {
  union { float f; unsigned int u; } c; c.f = f;
  unsigned int u = c.u;
  return (unsigned short)((u + 0x7FFFu + ((u >> 16) & 1u)) >> 16);
}
__device__ __forceinline__ float bf2f(unsigned short h) {
  return __uint_as_float(((unsigned int)h) << 16);
}

// ---------------------------------------------------------------------------
// cumsum over relation axis; emits fp32 cumsum (fallback path) AND transposed
// bf16 weights wtb[r][o][k] for the MFMA path. i indexes (d,o), o fastest.
__global__ __launch_bounds__(256) void cumsum_w(
    const float* __restrict__ wu, const float* __restrict__ wv,
    float* __restrict__ wcu, float* __restrict__ wcv,
    unsigned short* __restrict__ wtbu, unsigned short* __restrict__ wtbv) {
  int i = blockIdx.x * 256 + threadIdx.x;
  if (i >= D_IN * O_OUT) return;
  const int d = i >> 6;
  const int o = i & 63;
  float su = 0.f, sv = 0.f;
#pragma unroll
  for (int r = 0; r < R_SUP; ++r) {
    su += wu[r * D_IN * O_OUT + i];
    sv += wv[r * D_IN * O_OUT + i];
    wcu[r * D_IN * O_OUT + i] = su;
    wcv[r * D_IN * O_OUT + i] = sv;
    wtbu[((size_t)r * O_OUT + o) * D_IN + d] = f2bf(su);
    wtbv[((size_t)r * O_OUT + o) * D_IN + d] = f2bf(sv);
  }
}

__global__ __launch_bounds__(256) void zero_f32(float* __restrict__ p, int n4) {
  int i = blockIdx.x * 256 + threadIdx.x;
  int stride = gridDim.x * 256;
  float4 z = make_float4(0.f, 0.f, 0.f, 0.f);
  for (; i < n4; i += stride) ((float4*)p)[i] = z;
}

__global__ __launch_bounds__(256) void zero_i32(int* __restrict__ p, int n) {
  int i = blockIdx.x * 256 + threadIdx.x;
  int stride = gridDim.x * 256;
  for (; i < n; i += stride) p[i] = 0;
}

// ---------------------------------------------------------------------------
// MFMA GEMM body: tmp5[r][n][o] = bf16( sum_d x[n][d] * W[r][d][o] )
// Output staged through LDS so the 8KB tile store is fully coalesced.
__device__ __forceinline__ void gemm5_body(
    const float* __restrict__ x, const unsigned short* __restrict__ wtb,
    unsigned short* __restrict__ tmp5, size_t strideR, int N, int row0,
    unsigned short (*st)[72]) {
  const int tid = threadIdx.x;
  const int wave = tid >> 6;
  const int lane = tid & 63;
  const int m = lane & 15;
  const int q = lane >> 4;
  const int o0 = wave * 16;

  bf16x8 a[4][4];
#pragma unroll
  for (int rt = 0; rt < 4; ++rt) {
    int row = row0 + rt * 16 + m;
    if (row >= N) row = N - 1;  // clamp: loads harmless, stores guarded
    const float* px = x + (size_t)row * D_IN + q * 8;
#pragma unroll
    for (int k0 = 0; k0 < 4; ++k0) {
      float4 f0 = *(const float4*)(px + k0 * 32);
      float4 f1 = *(const float4*)(px + k0 * 32 + 4);
      bf16x8 t;
      t[0] = (short)f2bf(f0.x); t[1] = (short)f2bf(f0.y);
      t[2] = (short)f2bf(f0.z); t[3] = (short)f2bf(f0.w);
      t[4] = (short)f2bf(f1.x); t[5] = (short)f2bf(f1.y);
      t[6] = (short)f2bf(f1.z); t[7] = (short)f2bf(f1.w);
      a[rt][k0] = t;
    }
  }

  const int rr = tid >> 2;          // writeout row 0..63
  const int c0 = (tid & 3) * 16;    // writeout col chunk

  for (int r = 0; r < R_SUP; ++r) {
    bf16x8 b[4];
    const unsigned short* pw =
        wtb + ((size_t)r * O_OUT + o0 + m) * D_IN + q * 8;
#pragma unroll
    for (int k0 = 0; k0 < 4; ++k0)
      b[k0] = *(const bf16x8*)(pw + k0 * 32);
#pragma unroll
    for (int rt = 0; rt < 4; ++rt) {
      f32x4 acc = {0.f, 0.f, 0.f, 0.f};
#pragma unroll
      for (int k0 = 0; k0 < 4; ++k0)
        acc = __builtin_amdgcn_mfma_f32_16x16x32_bf16(a[rt][k0], b[k0], acc,
                                                      0, 0, 0);
#pragma unroll
      for (int reg = 0; reg < 4; ++reg)
        st[rt * 16 + q * 4 + reg][o0 + m] = f2bf(acc[reg]);
    }
    __syncthreads();
    // coalesced tile store: 256 threads x 32B cover the 8KB contiguous tile
    if (row0 + rr < N) {
      unsigned short* pz = tmp5 + (size_t)r * strideR + (size_t)row0 * O_OUT;
      *(int4*)(pz + rr * O_OUT + c0) = *(const int4*)&st[rr][c0];
      *(int4*)(pz + rr * O_OUT + c0 + 8) = *(const int4*)&st[rr][c0 + 8];
    }
    __syncthreads();
  }
}

// Single-direction GEMM (workspace-constrained path).
__global__ __launch_bounds__(256) void gemm5_mfma(
    const float* __restrict__ x, const unsigned short* __restrict__ wtb,
    unsigned short* __restrict__ tmp5, size_t strideR, int N) {
  __shared__ unsigned short st[64][72];
  gemm5_body(x, wtb, tmp5, strideR, N, blockIdx.x * 64, st);
}

// Dual-direction GEMM: one dispatch computes both tmp5 buffers.
__global__ __launch_bounds__(256) void gemm5_dual(
    const float* __restrict__ xv, const float* __restrict__ xu,
    const unsigned short* __restrict__ wtbv,
    const unsigned short* __restrict__ wtbu,
    unsigned short* __restrict__ t5B, unsigned short* __restrict__ t5A,
    size_t strideR, int NV, int NU, int gv) {
  __shared__ unsigned short st[64][72];
  const int bi = blockIdx.x;
  if (bi < gv)
    gemm5_body(xv, wtbv, t5B, strideR, NV, bi * 64, st);
  else
    gemm5_body(xu, wtbu, t5A, strideR, NU, (bi - gv) * 64, st);
}

// ---------------------------------------------------------------------------
// Coarse bucket histogram, both directions, int4-vectorized edge loads.
__global__ __launch_bounds__(256) void coarse_hist(
    const int* __restrict__ rows, const int* __restrict__ cols,
    int* __restrict__ cnt_u, int* __restrict__ cnt_v, int nE5,
    int nbu, int nbv) {
  __shared__ int hu[NBMAX], hv[NBMAX];
  const int tid = threadIdx.x;
  for (int t = tid; t < NBMAX; t += 256) { hu[t] = 0; hv[t] = 0; }
  __syncthreads();
  const int n4 = nE5 >> 2;
  int i = blockIdx.x * 256 + tid;
  int stride = gridDim.x * 256;
  for (; i < n4; i += stride) {
    int4 rr = ((const int4*)rows)[i];
    int4 cc = ((const int4*)cols)[i];
    atomicAdd(&hu[rr.x >> 8], 1); atomicAdd(&hu[rr.y >> 8], 1);
    atomicAdd(&hu[rr.z >> 8], 1); atomicAdd(&hu[rr.w >> 8], 1);
    atomicAdd(&hv[cc.x >> 8], 1); atomicAdd(&hv[cc.y >> 8], 1);
    atomicAdd(&hv[cc.z >> 8], 1); atomicAdd(&hv[cc.w >> 8], 1);
  }
  // tail
  for (i = (n4 << 2) + blockIdx.x * 256 + tid; i < nE5; i += stride) {
    atomicAdd(&hu[rows[i] >> 8], 1);
    atomicAdd(&hv[cols[i] >> 8], 1);
  }
  __syncthreads();
  for (int t = tid; t < nbu; t += 256) if (hu[t]) atomicAdd(&cnt_u[t], hu[t]);
  for (int t = tid; t < nbv; t += 256) if (hv[t]) atomicAdd(&cnt_v[t], hv[t]);
}

// Exclusive scan over coarse buckets. grid=2 (0->u, 1->v).
__global__ __launch_bounds__(512) void coarse_scan(
    int* __restrict__ cnt_u, int* __restrict__ cnt_v,
    int* __restrict__ cb_u, int* __restrict__ cb_v,
    int* __restrict__ gcur_u, int* __restrict__ gcur_v, int nbu, int nbv) {
  int* cnt = blockIdx.x ? cnt_v : cnt_u;
  int* cb  = blockIdx.x ? cb_v  : cb_u;
  int* gc  = blockIdx.x ? gcur_v : gcur_u;
  int nb   = blockIdx.x ? nbv   : nbu;
  __shared__ int sc[NBMAX];
  const int t = threadIdx.x;
  sc[t] = (t < nb) ? cnt[t] : 0;
  __syncthreads();
  for (int off = 1; off < NBMAX; off <<= 1) {
    int add = (t >= off) ? sc[t - off] : 0;
    __syncthreads();
    sc[t] += add;
    __syncthreads();
  }
  int excl = t ? sc[t - 1] : 0;
  if (t < nb) { cb[t] = excl; gc[t] = excl; }
  if (t == 0) cb[nb] = sc[NBMAX - 1];
}

// ---------------------------------------------------------------------------
// Coarse scatter, LDS-staged + bucket-sorted + coalesced run flush.
// One direction per block (blockIdx.x & 1). CHUNK=8192 (known-good config).
// payload: x = dst_lo<<20 | r<<17 | src, y = val bits
__global__ __launch_bounds__(512) void coarse_scatter(
    const int* __restrict__ rows, const int* __restrict__ cols,
    const float* __restrict__ vals, int* __restrict__ gcur_u,
    int* __restrict__ gcur_v, int2* __restrict__ mid_u,
    int2* __restrict__ mid_v, int nE5, int E, int nbu, int nbv) {
  __shared__ int2 buf[CHUNK];            // 64 KB
  __shared__ int h[NBMAX], sc[NBMAX], gb[NBMAX], cur[NBMAX];  // 8 KB
  const int tid = threadIdx.x;
  const int dir = blockIdx.x & 1;
  const int base = (blockIdx.x >> 1) * CHUNK;
  const int end = min(base + CHUNK, nE5);
  const int E2 = 2 * E, E3 = 3 * E, E4 = 4 * E;

  const int* ids   = dir ? cols : rows;
  const int* other = dir ? rows : cols;
  int* gcur = dir ? gcur_v : gcur_u;
  int2* mid = dir ? mid_v : mid_u;
  const int nb = dir ? nbv : nbu;

  h[tid] = 0;                // tid < 512 == NBMAX
  __syncthreads();
  // 1. histogram of this chunk
  for (int i = base + tid; i < end; i += 512)
    atomicAdd(&h[ids[i] >> 8], 1);
  __syncthreads();
  // 2. inclusive scan (Hillis-Steele, 512 threads == NBMAX elems)
  sc[tid] = h[tid];
  __syncthreads();
  for (int off = 1; off < NBMAX; off <<= 1) {
    int add = (tid >= off) ? sc[tid - off] : 0;
    __syncthreads();
    sc[tid] += add;
    __syncthreads();
  }
  // 3. reserve global runs; init local cursors to exclusive scan
  int excl = tid ? sc[tid - 1] : 0;
  cur[tid] = excl;
  if (tid < nb && h[tid]) gb[tid] = atomicAdd(&gcur[tid], h[tid]);
  __syncthreads();
  // 4. place payloads into LDS, bucket-sorted
  for (int i = base + tid; i < end; i += 512) {
    int id = ids[i];
    int src = other[i];
    int vb = __float_as_int(vals[i]);
    int r = (i >= E) + (i >= E2) + (i >= E3) + (i >= E4);
    int pos = atomicAdd(&cur[id >> 8], 1);
    buf[pos] = make_int2(((id & 255) << 20) | (r << 17) | src, vb);
  }
  __syncthreads();
  // 5. flush runs: wave w handles buckets w, w+8, ...; lanes consecutive
  const int wv = tid >> 6;
  const int lane = tid & 63;
  for (int b = wv; b < nb; b += 8) {
    int s = b ? sc[b - 1] : 0;
    int e = sc[b];
    if (s == e) continue;
    int2* dst = mid + gb[b];
    for (int j = s + lane; j < e; j += 64) dst[j - s] = buf[j];
  }
}

// ---------------------------------------------------------------------------
// Fused fine-sort + pull SpMM + ReLU body (r7-proven structure, FCAP=9216).
// Per LDS chunk: hist -> scan -> place sorted -> 32 groups of 16 lanes
// register-accumulate 8 dsts each with 8-deep global gathers.
__device__ __forceinline__ void spmm_body(
    const int2* __restrict__ mid, const int* __restrict__ cb,
    const unsigned short* __restrict__ tmp5, float* __restrict__ z,
    int Ndst, int strideR, int b, int2* buf, int* sc, int* cur) {
  const int tid = threadIdx.x;
  const int s = cb[b];
  const int e = cb[b + 1];
  const int d0 = b * 256;
  const int gid = tid >> 4;     // 32 groups of 16 lanes
  const int lane = tid & 15;
  const unsigned short* tl = tmp5 + lane * 4;  // per-lane 8B slice

  float4 acc[8];
#pragma unroll
  for (int k = 0; k < 8; ++k) acc[k] = make_float4(0.f, 0.f, 0.f, 0.f);

  for (int cs = s; cs < e; cs += FCAP) {
    const int ce = min(cs + FCAP, e);
    if (tid < 256) sc[tid] = 0;
    __syncthreads();
    // hist over this chunk
    for (int i = cs + tid; i < ce; i += 512)
      atomicAdd(&sc[(mid[i].x >> 20) & 255], 1);
    __syncthreads();
    // inclusive scan of 256 counters
    for (int off = 1; off < 256; off <<= 1) {
      int add = (tid < 256 && tid >= off) ? sc[tid - off] : 0;
      __syncthreads();
      if (tid < 256) sc[tid] += add;
      __syncthreads();
    }
    if (tid < 256) cur[tid] = tid ? sc[tid - 1] : 0;
    __syncthreads();
    // place sorted-by-dst into LDS; precompute tmp5 element offset
    for (int i = cs + tid; i < ce; i += 512) {
      int2 pk = mid[i];
      int dl = (pk.x >> 20) & 255;
      int r = (pk.x >> 17) & 7;
      int src = pk.x & 0x1FFFF;
      int pos = atomicAdd(&cur[dl], 1);
      buf[pos] = make_int2(r * strideR + (src << 6), pk.y);
    }
    __syncthreads();
    // gather + register accumulate: group gid owns dls gid, gid+32, ...
#pragma unroll
    for (int k = 0; k < 8; ++k) {
      const int dl = gid + (k << 5);
      int i = dl ? sc[dl - 1] : 0;
      const int re = sc[dl];
      float4 a = acc[k];
      for (; i + 8 <= re; i += 8) {
        int2 pk[8];
#pragma unroll
        for (int j = 0; j < 8; ++j) pk[j] = buf[i + j];
        ushort4 hh[8];
#pragma unroll
        for (int j = 0; j < 8; ++j)
          hh[j] = *(const ushort4*)(tl + (unsigned)pk[j].x);
#pragma unroll
        for (int j = 0; j < 8; ++j) {
          float v = __int_as_float(pk[j].y);
          a.x += v * bf2f(hh[j].x);
          a.y += v * bf2f(hh[j].y);
          a.z += v * bf2f(hh[j].z);
          a.w += v * bf2f(hh[j].w);
        }
      }
      for (; i < re; ++i) {
        int2 pk = buf[i];
        float v = __int_as_float(pk.y);
        ushort4 hh = *(const ushort4*)(tl + (unsigned)pk.x);
        a.x += v * bf2f(hh.x);
        a.y += v * bf2f(hh.y);
        a.z += v * bf2f(hh.z);
        a.w += v * bf2f(hh.w);
      }
      acc[k] = a;
    }
    __syncthreads();  // protect buf/sc reuse next chunk
  }
  // ReLU + coalesced writeout
#pragma unroll
  for (int k = 0; k < 8; ++k) {
    int d = d0 + gid + (k << 5);
    if (d < Ndst) {
      float4 o;
      o.x = fmaxf(acc[k].x, 0.f);
      o.y = fmaxf(acc[k].y, 0.f);
      o.z = fmaxf(acc[k].z, 0.f);
      o.w = fmaxf(acc[k].w, 0.f);
      ((float4*)(z + (size_t)d * O_OUT))[lane] = o;
    }
  }
}

// Single-direction launch (workspace-constrained path).
__global__ __launch_bounds__(512) void spmm_sorted(
    const int2* __restrict__ mid, const int* __restrict__ cb,
    const unsigned short* __restrict__ tmp5, float* __restrict__ z,
    int Ndst, int strideR) {
  __shared__ int2 buf[FCAP];
  __shared__ int sc[256], cur[256];
  spmm_body(mid, cb, tmp5, z, Ndst, strideR, blockIdx.x, buf, sc, cur);
}

// Dual-direction launch: grid = nbu + nbv. Doubles block supply (the r8/r9
// lesson: spmm was supply-limited at 391 blocks ~1.5/CU) with per-block work
// byte-identical to the proven r7 kernel. u-blocks first, v-blocks second:
// resident slots stay full through the u->v transition (no drain+ramp x2).
__global__ __launch_bounds__(512) void spmm_dual(
    const int2* __restrict__ mid_u, const int2* __restrict__ mid_v,
    const int* __restrict__ cb_u, const int* __restrict__ cb_v,
    const unsigned short* __restrict__ t5B,
    const unsigned short* __restrict__ t5A,
    float* __restrict__ out, int NU, int NV, int nbu, int strideR) {
  __shared__ int2 buf[FCAP];
  __shared__ int sc[256], cur[256];
  const int bi = blockIdx.x;
  if (bi < nbu)
    spmm_body(mid_u, cb_u, t5B, out, NU, strideR, bi, buf, sc, cur);
  else
    spmm_body(mid_v, cb_v, t5A, out + (size_t)NU * O_OUT, NV, strideR,
              bi - nbu, buf, sc, cur);
}

// ---------------------------------------------------------------------------
// Fallback (push-atomic) kernels — only used if ws_size is tiny.
__global__ __launch_bounds__(256) void gemm64(
    const float* __restrict__ x, const float* __restrict__ w,
    float* __restrict__ out, int N) {
  __shared__ float sXT[D_IN][68];
  __shared__ float sW[D_IN][O_OUT];
  const int tid = threadIdx.x;
  const int row0 = blockIdx.x * 64;
  for (int i = tid; i < 2048; i += 256) {
    int d = i >> 4;
    int o4 = i & 15;
    ((float4*)&sW[d][0])[o4] = ((const float4*)w)[i];
  }
  for (int i = tid; i < 2048; i += 256) {
    int rl = i >> 5;
    int d4 = i & 31;
    int row = row0 + rl;
    float4 xv = make_float4(0.f, 0.f, 0.f, 0.f);
    if (row < N) xv = ((const float4*)x)[(size_t)row * 32 + d4];
    sXT[d4 * 4 + 0][rl] = xv.x;
    sXT[d4 * 4 + 1][rl] = xv.y;
    sXT[d4 * 4 + 2][rl] = xv.z;
    sXT[d4 * 4 + 3][rl] = xv.w;
  }
  __syncthreads();
  const int col4 = (tid & 15) * 4;
  const int row4 = (tid >> 4) * 4;
  float acc[4][4] = {};
#pragma unroll 8
  for (int d = 0; d < D_IN; ++d) {
    float4 xv = *(const float4*)&sXT[d][row4];
    float4 wv = *(const float4*)&sW[d][col4];
    acc[0][0] += xv.x * wv.x; acc[0][1] += xv.x * wv.y; acc[0][2] += xv.x * wv.z; acc[0][3] += xv.x * wv.w;
    acc[1][0] += xv.y * wv.x; acc[1][1] += xv.y * wv.y; acc[1][2] += xv.y * wv.z; acc[1][3] += xv.y * wv.w;
    acc[2][0] += xv.z * wv.x; acc[2][1] += xv.z * wv.y; acc[2][2] += xv.z * wv.z; acc[2][3] += xv.z * wv.w;
    acc[3][0] += xv.w * wv.x; acc[3][1] += xv.w * wv.y; acc[3][2] += xv.w * wv.z; acc[3][3] += xv.w * wv.w;
  }
#pragma unroll
  for (int i = 0; i < 4; ++i) {
    int row = row0 + row4 + i;
    if (row < N)
      *(float4*)&out[row * O_OUT + col4] =
          make_float4(acc[i][0], acc[i][1], acc[i][2], acc[i][3]);
  }
}

__global__ __launch_bounds__(256) void spmm_push(
    const int* __restrict__ dst, const int* __restrict__ src,
    const float* __restrict__ vals, const float* __restrict__ tmp,
    float* __restrict__ z, int E) {
  int t = blockIdx.x * 256 + threadIdx.x;
  int e = t >> 4;
  int lane = t & 15;
  if (e >= E) return;
  int d_ = dst[e];
  int s_ = src[e];
  float v = vals[e];
  float4 f = ((const float4*)tmp)[s_ * 16 + lane];
  float* zp = z + (size_t)d_ * O_OUT + lane * 4;
  atomicAdd(zp + 0, v * f.x);
  atomicAdd(zp + 1, v * f.y);
  atomicAdd(zp + 2, v * f.z);
  atomicAdd(zp + 3, v * f.w);
}

__global__ __launch_bounds__(256) void relu_f32(float* __restrict__ p, int n4) {
  int i = blockIdx.x * 256 + threadIdx.x;
  int stride = gridDim.x * 256;
  for (; i < n4; i += stride) {
    float4 v = ((float4*)p)[i];
    v.x = v.x > 0.f ? v.x : 0.f;
    v.y = v.y > 0.f ? v.y : 0.f;
    v.z = v.z > 0.f ? v.z : 0.f;
    v.w = v.w > 0.f ? v.w : 0.f;
    ((float4*)p)[i] = v;
  }
}

// ---------------------------------------------------------------------------
extern "C" void kernel_launch(void* const* d_in, const int* in_sizes, int n_in,
                              void* d_out, int out_size, void* d_ws, size_t ws_size,
                              hipStream_t stream) {
  const float* x_u      = (const float*)d_in[0];
  const float* x_v      = (const float*)d_in[1];
  const int*   sup_rows = (const int*)d_in[2];
  const int*   sup_cols = (const int*)d_in[3];
  const float* sup_vals = (const float*)d_in[4];
  const float* wu       = (const float*)d_in[5];
  const float* wv       = (const float*)d_in[6];

  const int NU = in_sizes[0] / D_IN;
  const int NV = in_sizes[1] / D_IN;
  const int E  = in_sizes[2] / R_SUP;
  const int Nmax = NU > NV ? NU : NV;
  const int nE5 = R_SUP * E;
  const int nbu = (NU + 255) / 256;
  const int nbv = (NV + 255) / 256;
  const int nbmax = nbu > nbv ? nbu : nbv;

  float* out = (float*)d_out;
  float* z_u = out;
  float* z_v = out + (size_t)NU * O_OUT;

  const int WDO = R_SUP * D_IN * O_OUT;  // 40960
  const size_t strideR = (size_t)Nmax * O_OUT;
  const size_t bpad = (size_t)nbmax + 16;

  const size_t mid_bytes = (((size_t)nE5 * 8) + 255) & ~(size_t)255;
  const size_t t5_bytes = (strideR * R_SUP * 2 + 255) & ~(size_t)255;

  const size_t fixed = (size_t)2 * WDO * 4 + (size_t)2 * WDO * 2 +
                       6 * bpad * 4 + 512;
  const size_t need2 = 2 * mid_bytes + 2 * t5_bytes + fixed;  // dual tmp5
  const size_t need1 = 2 * mid_bytes + t5_bytes + fixed;      // single tmp5

  if (ws_size >= need1 && nbmax <= NBMAX && Nmax < (1 << 17)) {
    const bool dual = (ws_size >= need2);
    char* base = (char*)d_ws;
    int2* mid_u = (int2*)base;
    int2* mid_v = (int2*)(base + mid_bytes);
    unsigned short* t5B = (unsigned short*)(base + 2 * mid_bytes);
    unsigned short* t5A = dual ? (unsigned short*)(base + 2 * mid_bytes + t5_bytes)
                               : t5B;   // single-buffer mode aliases
    char* tail = (char*)(base + 2 * mid_bytes + (dual ? 2 : 1) * t5_bytes);
    float* wcu = (float*)tail;
    float* wcv = wcu + WDO;
    unsigned short* wtbu = (unsigned short*)(wcv + WDO);
    unsigned short* wtbv = wtbu + WDO;
    int* cnt_u = (int*)(wtbv + WDO);
    int* cnt_v = cnt_u + bpad;
    int* cb_u  = cnt_v + bpad;
    int* cb_v  = cb_u + bpad;
    int* gcur_u = cb_v + bpad;
    int* gcur_v = gcur_u + bpad;

    cumsum_w<<<(D_IN * O_OUT + 255) / 256, 256, 0, stream>>>(
        wu, wv, wcu, wcv, wtbu, wtbv);
    zero_i32<<<(2 * (int)bpad + 255) / 256, 256, 0, stream>>>(cnt_u, 2 * (int)bpad);
    coarse_hist<<<512, 256, 0, stream>>>(sup_rows, sup_cols, cnt_u, cnt_v,
                                         nE5, nbu, nbv);
    coarse_scan<<<2, 512, 0, stream>>>(cnt_u, cnt_v, cb_u, cb_v, gcur_u,
                                       gcur_v, nbu, nbv);
    coarse_scatter<<<2 * ((nE5 + CHUNK - 1) / CHUNK), 512, 0, stream>>>(
        sup_rows, sup_cols, sup_vals, gcur_u, gcur_v, mid_u, mid_v, nE5, E,
        nbu, nbv);

    if (dual) {
      const int gv = (NV + 63) / 64;
      const int gu = (NU + 63) / 64;
      gemm5_dual<<<gv + gu, 256, 0, stream>>>(x_v, x_u, wtbv, wtbu, t5B, t5A,
                                              strideR, NV, NU, gv);
      spmm_dual<<<nbu + nbv, 512, 0, stream>>>(mid_u, mid_v, cb_u, cb_v, t5B,
                                               t5A, out, NU, NV, nbu,
                                               (int)strideR);
    } else {
      // r7-proven serial sequence (single tmp5)
      gemm5_mfma<<<(NV + 63) / 64, 256, 0, stream>>>(x_v, wtbv, t5B, strideR, NV);
      spmm_sorted<<<nbu, 512, 0, stream>>>(mid_u, cb_u, t5B, z_u, NU,
                                           (int)strideR);
      gemm5_mfma<<<(NU + 63) / 64, 256, 0, stream>>>(x_u, wtbu, t5B, strideR, NU);
      spmm_sorted<<<nbv, 512, 0, stream>>>(mid_v, cb_v, t5B, z_v, NV,
                                           (int)strideR);
    }
  } else {
    // ---- fallback: push-atomic path ----
    float* wcu = (float*)d_ws;
    float* wcv = wcu + WDO;
    unsigned short* wtbu = (unsigned short*)(wcv + WDO);
    unsigned short* wtbv = wtbu + WDO;
    float* tmp = (float*)(wtbv + WDO);
    const int n4_out = out_size / 4;
    cumsum_w<<<(D_IN * O_OUT + 255) / 256, 256, 0, stream>>>(
        wu, wv, wcu, wcv, wtbu, wtbv);
    zero_f32<<<1024, 256, 0, stream>>>(out, n4_out);
    const int spmm_blocks = (E * 16 + 255) / 256;
    for (int r = 0; r < R_SUP; ++r) {
      const int* rws = sup_rows + (size_t)r * E;
      const int* cls = sup_cols + (size_t)r * E;
      const float* vls = sup_vals + (size_t)r * E;
      gemm64<<<(NV + 63) / 64, 256, 0, stream>>>(x_v, wcv + r * D_IN * O_OUT, tmp, NV);
      spmm_push<<<spmm_blocks, 256, 0, stream>>>(rws, cls, vls, tmp, z_u, E);
      gemm64<<<(NU + 63) / 64, 256, 0, stream>>>(x_u, wcu + r * D_IN * O_OUT, tmp, NU);
      spmm_push<<<spmm_blocks, 256, 0, stream>>>(cls, rws, vls, tmp, z_v, E);
    }
    relu_f32<<<1024, 256, 0, stream>>>(out, n4_out);
  }
}

// Round 11
// 446.069 us; speedup vs baseline: 1.2035x; 1.1235x over previous
//
#include <hip/hip_runtime.h>
#include <hip/hip_bf16.h>

// Problem constants (shapes fixed by reference; N's derived from in_sizes)
#define R_SUP 5
#define D_IN 128
#define O_OUT 64
#define NBMAX 512          // max coarse buckets
#define CHUNK 8192         // edges per workgroup in coarse_scatter
#define FCAP 9216          // LDS-staged sorted entries per chunk (72 KB)

typedef __attribute__((ext_vector_type(8))) short bf16x8;
typedef __attribute__((ext_vector_type(4))) float f32x4;

// fp32 -> bf16 round-to-nearest-even
__device__ __forceinline__ unsigned short f2bf(float f) {
  union { float f; unsigned int u; } c; c.f = f;
  unsigned int u = c.u;
  return (unsigned short)((u + 0x7FFFu + ((u >> 16) & 1u)) >> 16);
}
__device__ __forceinline__ float bf2f(unsigned short h) {
  return __uint_as_float(((unsigned int)h) << 16);
}

// ---------------------------------------------------------------------------
// cumsum over relation axis; emits fp32 cumsum (fallback path) AND transposed
// bf16 weights wtb[r][o][k] for the MFMA path. i indexes (d,o), o fastest.
__global__ __launch_bounds__(256) void cumsum_w(
    const float* __restrict__ wu, const float* __restrict__ wv,
    float* __restrict__ wcu, float* __restrict__ wcv,
    unsigned short* __restrict__ wtbu, unsigned short* __restrict__ wtbv) {
  int i = blockIdx.x * 256 + threadIdx.x;
  if (i >= D_IN * O_OUT) return;
  const int d = i >> 6;
  const int o = i & 63;
  float su = 0.f, sv = 0.f;
#pragma unroll
  for (int r = 0; r < R_SUP; ++r) {
    su += wu[r * D_IN * O_OUT + i];
    sv += wv[r * D_IN * O_OUT + i];
    wcu[r * D_IN * O_OUT + i] = su;
    wcv[r * D_IN * O_OUT + i] = sv;
    wtbu[((size_t)r * O_OUT + o) * D_IN + d] = f2bf(su);
    wtbv[((size_t)r * O_OUT + o) * D_IN + d] = f2bf(sv);
  }
}

__global__ __launch_bounds__(256) void zero_f32(float* __restrict__ p, int n4) {
  int i = blockIdx.x * 256 + threadIdx.x;
  int stride = gridDim.x * 256;
  float4 z = make_float4(0.f, 0.f, 0.f, 0.f);
  for (; i < n4; i += stride) ((float4*)p)[i] = z;
}

__global__ __launch_bounds__(256) void zero_i32(int* __restrict__ p, int n) {
  int i = blockIdx.x * 256 + threadIdx.x;
  int stride = gridDim.x * 256;
  for (; i < n; i += stride) p[i] = 0;
}

// ---------------------------------------------------------------------------
// MFMA batched GEMM: tmp5[r][n][o] = bf16( sum_d x[n][d] * W[r][d][o] )
// x tile is loaded + converted ONCE into a swizzled bf16 LDS buffer (the old
// code had every wave redundantly load/convert the same A tile: 128KB global
// + 32K cvts per block for a 32KB tile). Fragments then come from ds_read.
// XOR swizzle (byte ^= (row&7)<<4) keeps 16B alignment, ~2-way banks.
__global__ __launch_bounds__(256) void gemm5_mfma(
    const float* __restrict__ x,
    const unsigned short* __restrict__ wtb,
    unsigned short* __restrict__ tmp5, size_t strideR, int N) {
  __shared__ unsigned short lx[64 * 128];   // swizzled bf16 x tile, 16KB
  __shared__ unsigned short st[64][72];     // coalesced-store staging, 18KB
  const int tid = threadIdx.x;
  const int row0 = blockIdx.x * 64;
  const int wave = tid >> 6;
  const int lane = tid & 63;
  const int m = lane & 15;
  const int q = lane >> 4;
  const int o0 = wave * 16;

  // cooperative load + convert of the 64x128 fp32 tile (32 elems/thread)
#pragma unroll
  for (int it = 0; it < 4; ++it) {
    int idx = it * 2048 + tid * 8;   // element index in tile, 8 per iter
    int row = idx >> 7;
    int col = idx & 127;
    int grow = row0 + row;
    if (grow >= N) grow = N - 1;     // clamp: loads harmless, stores guarded
    const float* px = x + (size_t)grow * D_IN + col;
    float4 f0 = *(const float4*)px;
    float4 f1 = *(const float4*)(px + 4);
    int4 pk4;
    pk4.x = (int)f2bf(f0.x) | ((int)f2bf(f0.y) << 16);
    pk4.y = (int)f2bf(f0.z) | ((int)f2bf(f0.w) << 16);
    pk4.z = (int)f2bf(f1.x) | ((int)f2bf(f1.y) << 16);
    pk4.w = (int)f2bf(f1.z) | ((int)f2bf(f1.w) << 16);
    int byte = row * 256 + ((col * 2) ^ ((row & 7) << 4));
    *(int4*)((char*)lx + byte) = pk4;
  }
  __syncthreads();

  bf16x8 a[4][4];
#pragma unroll
  for (int rt = 0; rt < 4; ++rt) {
    const int rbase = (rt * 16 + m) * 256;
    const int sw = (m & 7) << 4;
#pragma unroll
    for (int k0 = 0; k0 < 4; ++k0)
      a[rt][k0] =
          *(const bf16x8*)((const char*)lx + rbase + ((q * 16 + k0 * 64) ^ sw));
  }

  const int rr = tid >> 2;          // writeout row 0..63
  const int c0 = (tid & 3) * 16;    // writeout col chunk

  for (int r = 0; r < R_SUP; ++r) {
    bf16x8 b[4];
    const unsigned short* pw =
        wtb + ((size_t)r * O_OUT + o0 + m) * D_IN + q * 8;
#pragma unroll
    for (int k0 = 0; k0 < 4; ++k0)
      b[k0] = *(const bf16x8*)(pw + k0 * 32);
#pragma unroll
    for (int rt = 0; rt < 4; ++rt) {
      f32x4 acc = {0.f, 0.f, 0.f, 0.f};
#pragma unroll
      for (int k0 = 0; k0 < 4; ++k0)
        acc = __builtin_amdgcn_mfma_f32_16x16x32_bf16(a[rt][k0], b[k0], acc,
                                                      0, 0, 0);
#pragma unroll
      for (int reg = 0; reg < 4; ++reg)
        st[rt * 16 + q * 4 + reg][o0 + m] = f2bf(acc[reg]);
    }
    __syncthreads();
    // coalesced tile store: 256 threads x 32B cover the 8KB contiguous tile
    if (row0 + rr < N) {
      unsigned short* pz = tmp5 + (size_t)r * strideR + (size_t)row0 * O_OUT;
      *(int4*)(pz + rr * O_OUT + c0) = *(const int4*)&st[rr][c0];
      *(int4*)(pz + rr * O_OUT + c0 + 8) = *(const int4*)&st[rr][c0 + 8];
    }
    __syncthreads();
  }
}

// ---------------------------------------------------------------------------
// Coarse bucket histogram, both directions, int4-vectorized edge loads.
__global__ __launch_bounds__(256) void coarse_hist(
    const int* __restrict__ rows, const int* __restrict__ cols,
    int* __restrict__ cnt_u, int* __restrict__ cnt_v, int nE5,
    int nbu, int nbv) {
  __shared__ int hu[NBMAX], hv[NBMAX];
  const int tid = threadIdx.x;
  for (int t = tid; t < NBMAX; t += 256) { hu[t] = 0; hv[t] = 0; }
  __syncthreads();
  const int n4 = nE5 >> 2;
  int i = blockIdx.x * 256 + tid;
  int stride = gridDim.x * 256;
  for (; i < n4; i += stride) {
    int4 rr = ((const int4*)rows)[i];
    int4 cc = ((const int4*)cols)[i];
    atomicAdd(&hu[rr.x >> 8], 1); atomicAdd(&hu[rr.y >> 8], 1);
    atomicAdd(&hu[rr.z >> 8], 1); atomicAdd(&hu[rr.w >> 8], 1);
    atomicAdd(&hv[cc.x >> 8], 1); atomicAdd(&hv[cc.y >> 8], 1);
    atomicAdd(&hv[cc.z >> 8], 1); atomicAdd(&hv[cc.w >> 8], 1);
  }
  // tail
  for (i = (n4 << 2) + blockIdx.x * 256 + tid; i < nE5; i += stride) {
    atomicAdd(&hu[rows[i] >> 8], 1);
    atomicAdd(&hv[cols[i] >> 8], 1);
  }
  __syncthreads();
  for (int t = tid; t < nbu; t += 256) if (hu[t]) atomicAdd(&cnt_u[t], hu[t]);
  for (int t = tid; t < nbv; t += 256) if (hv[t]) atomicAdd(&cnt_v[t], hv[t]);
}

// Exclusive scan over coarse buckets. grid=2 (0->u, 1->v).
__global__ __launch_bounds__(512) void coarse_scan(
    int* __restrict__ cnt_u, int* __restrict__ cnt_v,
    int* __restrict__ cb_u, int* __restrict__ cb_v,
    int* __restrict__ gcur_u, int* __restrict__ gcur_v, int nbu, int nbv) {
  int* cnt = blockIdx.x ? cnt_v : cnt_u;
  int* cb  = blockIdx.x ? cb_v  : cb_u;
  int* gc  = blockIdx.x ? gcur_v : gcur_u;
  int nb   = blockIdx.x ? nbv   : nbu;
  __shared__ int sc[NBMAX];
  const int t = threadIdx.x;
  sc[t] = (t < nb) ? cnt[t] : 0;
  __syncthreads();
  for (int off = 1; off < NBMAX; off <<= 1) {
    int add = (t >= off) ? sc[t - off] : 0;
    __syncthreads();
    sc[t] += add;
    __syncthreads();
  }
  int excl = t ? sc[t - 1] : 0;
  if (t < nb) { cb[t] = excl; gc[t] = excl; }
  if (t == 0) cb[nb] = sc[NBMAX - 1];
}

// ---------------------------------------------------------------------------
// Coarse scatter, LDS-staged + bucket-sorted + coalesced run flush.
// One direction per block (blockIdx.x & 1). CHUNK=8192 (known-good config).
// payload: x = dst_lo<<20 | r<<17 | src, y = val bits
__global__ __launch_bounds__(512) void coarse_scatter(
    const int* __restrict__ rows, const int* __restrict__ cols,
    const float* __restrict__ vals, int* __restrict__ gcur_u,
    int* __restrict__ gcur_v, int2* __restrict__ mid_u,
    int2* __restrict__ mid_v, int nE5, int E, int nbu, int nbv) {
  __shared__ int2 buf[CHUNK];            // 64 KB
  __shared__ int h[NBMAX], sc[NBMAX], gb[NBMAX], cur[NBMAX];  // 8 KB
  const int tid = threadIdx.x;
  const int dir = blockIdx.x & 1;
  const int base = (blockIdx.x >> 1) * CHUNK;
  const int end = min(base + CHUNK, nE5);
  const int E2 = 2 * E, E3 = 3 * E, E4 = 4 * E;

  const int* ids   = dir ? cols : rows;
  const int* other = dir ? rows : cols;
  int* gcur = dir ? gcur_v : gcur_u;
  int2* mid = dir ? mid_v : mid_u;
  const int nb = dir ? nbv : nbu;

  h[tid] = 0;                // tid < 512 == NBMAX
  __syncthreads();
  // 1. histogram of this chunk
  for (int i = base + tid; i < end; i += 512)
    atomicAdd(&h[ids[i] >> 8], 1);
  __syncthreads();
  // 2. inclusive scan (Hillis-Steele, 512 threads == NBMAX elems)
  sc[tid] = h[tid];
  __syncthreads();
  for (int off = 1; off < NBMAX; off <<= 1) {
    int add = (tid >= off) ? sc[tid - off] : 0;
    __syncthreads();
    sc[tid] += add;
    __syncthreads();
  }
  // 3. reserve global runs; init local cursors to exclusive scan
  int excl = tid ? sc[tid - 1] : 0;
  cur[tid] = excl;
  if (tid < nb && h[tid]) gb[tid] = atomicAdd(&gcur[tid], h[tid]);
  __syncthreads();
  // 4. place payloads into LDS, bucket-sorted
  for (int i = base + tid; i < end; i += 512) {
    int id = ids[i];
    int src = other[i];
    int vb = __float_as_int(vals[i]);
    int r = (i >= E) + (i >= E2) + (i >= E3) + (i >= E4);
    int pos = atomicAdd(&cur[id >> 8], 1);
    buf[pos] = make_int2(((id & 255) << 20) | (r << 17) | src, vb);
  }
  __syncthreads();
  // 5. flush runs: wave w handles buckets w, w+8, ...; lanes consecutive
  const int wv = tid >> 6;
  const int lane = tid & 63;
  for (int b = wv; b < nb; b += 8) {
    int s = b ? sc[b - 1] : 0;
    int e = sc[b];
    if (s == e) continue;
    int2* dst = mid + gb[b];
    for (int j = s + lane; j < e; j += 64) dst[j - s] = buf[j];
  }
}

// ---------------------------------------------------------------------------
// Fused fine-sort + pull SpMM + ReLU (r7-proven structure, FCAP=9216).
// Per LDS chunk: hist -> scan -> place sorted -> 32 groups of 16 lanes
// register-accumulate 8 dsts each. Gather batches deepened to 16 (r7 ran
// 8-deep at 3.05 TB/s vs the pattern's demonstrated 3.45; ~115 VGPR still
// fits 4 waves/SIMD at the 2-block LDS residency).
__global__ __launch_bounds__(512) void spmm_sorted(
    const int2* __restrict__ mid, const int* __restrict__ cb,
    const unsigned short* __restrict__ tmp5, float* __restrict__ z,
    int Ndst, int strideR) {
  __shared__ int2 buf[FCAP];           // 73728 B
  __shared__ int sc[256], cur[256];    // 2 KB
  const int tid = threadIdx.x;
  const int b = blockIdx.x;
  const int s = cb[b];
  const int e = cb[b + 1];
  const int d0 = b * 256;
  const int gid = tid >> 4;     // 32 groups of 16 lanes
  const int lane = tid & 15;
  const unsigned short* tl = tmp5 + lane * 4;  // per-lane 8B slice

  float4 acc[8];
#pragma unroll
  for (int k = 0; k < 8; ++k) acc[k] = make_float4(0.f, 0.f, 0.f, 0.f);

  for (int cs = s; cs < e; cs += FCAP) {
    const int ce = min(cs + FCAP, e);
    if (tid < 256) sc[tid] = 0;
    __syncthreads();
    // hist over this chunk
    for (int i = cs + tid; i < ce; i += 512)
      atomicAdd(&sc[(mid[i].x >> 20) & 255], 1);
    __syncthreads();
    // inclusive scan of 256 counters
    for (int off = 1; off < 256; off <<= 1) {
      int add = (tid < 256 && tid >= off) ? sc[tid - off] : 0;
      __syncthreads();
      if (tid < 256) sc[tid] += add;
      __syncthreads();
    }
    if (tid < 256) cur[tid] = tid ? sc[tid - 1] : 0;
    __syncthreads();
    // place sorted-by-dst into LDS; precompute tmp5 element offset
    for (int i = cs + tid; i < ce; i += 512) {
      int2 pk = mid[i];
      int dl = (pk.x >> 20) & 255;
      int r = (pk.x >> 17) & 7;
      int src = pk.x & 0x1FFFF;
      int pos = atomicAdd(&cur[dl], 1);
      buf[pos] = make_int2(r * strideR + (src << 6), pk.y);
    }
    __syncthreads();
    // gather + register accumulate: group gid owns dls gid, gid+32, ...
#pragma unroll
    for (int k = 0; k < 8; ++k) {
      const int dl = gid + (k << 5);
      int i = dl ? sc[dl - 1] : 0;
      const int re = sc[dl];
      float4 a = acc[k];
      for (; i + 16 <= re; i += 16) {
        int2 pk[16];
#pragma unroll
        for (int j = 0; j < 16; ++j) pk[j] = buf[i + j];
        ushort4 hh[16];
#pragma unroll
        for (int j = 0; j < 16; ++j)
          hh[j] = *(const ushort4*)(tl + (unsigned)pk[j].x);
#pragma unroll
        for (int j = 0; j < 16; ++j) {
          float v = __int_as_float(pk[j].y);
          a.x += v * bf2f(hh[j].x);
          a.y += v * bf2f(hh[j].y);
          a.z += v * bf2f(hh[j].z);
          a.w += v * bf2f(hh[j].w);
        }
      }
      for (; i + 8 <= re; i += 8) {
        int2 pk[8];
#pragma unroll
        for (int j = 0; j < 8; ++j) pk[j] = buf[i + j];
        ushort4 hh[8];
#pragma unroll
        for (int j = 0; j < 8; ++j)
          hh[j] = *(const ushort4*)(tl + (unsigned)pk[j].x);
#pragma unroll
        for (int j = 0; j < 8; ++j) {
          float v = __int_as_float(pk[j].y);
          a.x += v * bf2f(hh[j].x);
          a.y += v * bf2f(hh[j].y);
          a.z += v * bf2f(hh[j].z);
          a.w += v * bf2f(hh[j].w);
        }
      }
      for (; i < re; ++i) {
        int2 pk = buf[i];
        float v = __int_as_float(pk.y);
        ushort4 hh = *(const ushort4*)(tl + (unsigned)pk.x);
        a.x += v * bf2f(hh.x);
        a.y += v * bf2f(hh.y);
        a.z += v * bf2f(hh.z);
        a.w += v * bf2f(hh.w);
      }
      acc[k] = a;
    }
    __syncthreads();  // protect buf/sc reuse next chunk
  }
  // ReLU + coalesced writeout
#pragma unroll
  for (int k = 0; k < 8; ++k) {
    int d = d0 + gid + (k << 5);
    if (d < Ndst) {
      float4 o;
      o.x = fmaxf(acc[k].x, 0.f);
      o.y = fmaxf(acc[k].y, 0.f);
      o.z = fmaxf(acc[k].z, 0.f);
      o.w = fmaxf(acc[k].w, 0.f);
      ((float4*)(z + (size_t)d * O_OUT))[lane] = o;
    }
  }
}

// ---------------------------------------------------------------------------
// Fallback (push-atomic) kernels — only used if ws_size is tiny.
__global__ __launch_bounds__(256) void gemm64(
    const float* __restrict__ x, const float* __restrict__ w,
    float* __restrict__ out, int N) {
  __shared__ float sXT[D_IN][68];
  __shared__ float sW[D_IN][O_OUT];
  const int tid = threadIdx.x;
  const int row0 = blockIdx.x * 64;
  for (int i = tid; i < 2048; i += 256) {
    int d = i >> 4;
    int o4 = i & 15;
    ((float4*)&sW[d][0])[o4] = ((const float4*)w)[i];
  }
  for (int i = tid; i < 2048; i += 256) {
    int rl = i >> 5;
    int d4 = i & 31;
    int row = row0 + rl;
    float4 xv = make_float4(0.f, 0.f, 0.f, 0.f);
    if (row < N) xv = ((const float4*)x)[(size_t)row * 32 + d4];
    sXT[d4 * 4 + 0][rl] = xv.x;
    sXT[d4 * 4 + 1][rl] = xv.y;
    sXT[d4 * 4 + 2][rl] = xv.z;
    sXT[d4 * 4 + 3][rl] = xv.w;
  }
  __syncthreads();
  const int col4 = (tid & 15) * 4;
  const int row4 = (tid >> 4) * 4;
  float acc[4][4] = {};
#pragma unroll 8
  for (int d = 0; d < D_IN; ++d) {
    float4 xv = *(const float4*)&sXT[d][row4];
    float4 wv = *(const float4*)&sW[d][col4];
    acc[0][0] += xv.x * wv.x; acc[0][1] += xv.x * wv.y; acc[0][2] += xv.x * wv.z; acc[0][3] += xv.x * wv.w;
    acc[1][0] += xv.y * wv.x; acc[1][1] += xv.y * wv.y; acc[1][2] += xv.y * wv.z; acc[1][3] += xv.y * wv.w;
    acc[2][0] += xv.z * wv.x; acc[2][1] += xv.z * wv.y; acc[2][2] += xv.z * wv.z; acc[2][3] += xv.z * wv.w;
    acc[3][0] += xv.w * wv.x; acc[3][1] += xv.w * wv.y; acc[3][2] += xv.w * wv.z; acc[3][3] += xv.w * wv.w;
  }
#pragma unroll
  for (int i = 0; i < 4; ++i) {
    int row = row0 + row4 + i;
    if (row < N)
      *(float4*)&out[row * O_OUT + col4] =
          make_float4(acc[i][0], acc[i][1], acc[i][2], acc[i][3]);
  }
}

__global__ __launch_bounds__(256) void spmm_push(
    const int* __restrict__ dst, const int* __restrict__ src,
    const float* __restrict__ vals, const float* __restrict__ tmp,
    float* __restrict__ z, int E) {
  int t = blockIdx.x * 256 + threadIdx.x;
  int e = t >> 4;
  int lane = t & 15;
  if (e >= E) return;
  int d_ = dst[e];
  int s_ = src[e];
  float v = vals[e];
  float4 f = ((const float4*)tmp)[s_ * 16 + lane];
  float* zp = z + (size_t)d_ * O_OUT + lane * 4;
  atomicAdd(zp + 0, v * f.x);
  atomicAdd(zp + 1, v * f.y);
  atomicAdd(zp + 2, v * f.z);
  atomicAdd(zp + 3, v * f.w);
}

__global__ __launch_bounds__(256) void relu_f32(float* __restrict__ p, int n4) {
  int i = blockIdx.x * 256 + threadIdx.x;
  int stride = gridDim.x * 256;
  for (; i < n4; i += stride) {
    float4 v = ((float4*)p)[i];
    v.x = v.x > 0.f ? v.x : 0.f;
    v.y = v.y > 0.f ? v.y : 0.f;
    v.z = v.z > 0.f ? v.z : 0.f;
    v.w = v.w > 0.f ? v.w : 0.f;
    ((float4*)p)[i] = v;
  }
}

// ---------------------------------------------------------------------------
extern "C" void kernel_launch(void* const* d_in, const int* in_sizes, int n_in,
                              void* d_out, int out_size, void* d_ws, size_t ws_size,
                              hipStream_t stream) {
  const float* x_u      = (const float*)d_in[0];
  const float* x_v      = (const float*)d_in[1];
  const int*   sup_rows = (const int*)d_in[2];
  const int*   sup_cols = (const int*)d_in[3];
  const float* sup_vals = (const float*)d_in[4];
  const float* wu       = (const float*)d_in[5];
  const float* wv       = (const float*)d_in[6];

  const int NU = in_sizes[0] / D_IN;
  const int NV = in_sizes[1] / D_IN;
  const int E  = in_sizes[2] / R_SUP;
  const int Nmax = NU > NV ? NU : NV;
  const int nE5 = R_SUP * E;
  const int nbu = (NU + 255) / 256;
  const int nbv = (NV + 255) / 256;
  const int nbmax = nbu > nbv ? nbu : nbv;

  float* out = (float*)d_out;
  float* z_u = out;
  float* z_v = out + (size_t)NU * O_OUT;

  const int WDO = R_SUP * D_IN * O_OUT;  // 40960
  const size_t strideR = (size_t)Nmax * O_OUT;
  const size_t bpad = (size_t)nbmax + 16;

  const size_t mid_bytes = (((size_t)nE5 * 8) + 255) & ~(size_t)255;
  const size_t t5_bytes = (strideR * R_SUP * 2 + 255) & ~(size_t)255;

  // --- Radix path workspace layout (r7-proven: single tmp5) ---
  const size_t needR = 2 * mid_bytes + t5_bytes + (size_t)2 * WDO * 4 +
                       (size_t)2 * WDO * 2 + 6 * bpad * 4 + 512;

  if (ws_size >= needR && nbmax <= NBMAX && Nmax < (1 << 17)) {
    char* base = (char*)d_ws;
    int2* mid_u = (int2*)base;
    int2* mid_v = (int2*)(base + mid_bytes);
    unsigned short* tmp5 = (unsigned short*)(base + 2 * mid_bytes);
    float* wcu = (float*)(base + 2 * mid_bytes + t5_bytes);
    float* wcv = wcu + WDO;
    unsigned short* wtbu = (unsigned short*)(wcv + WDO);
    unsigned short* wtbv = wtbu + WDO;
    int* cnt_u = (int*)(wtbv + WDO);
    int* cnt_v = cnt_u + bpad;
    int* cb_u  = cnt_v + bpad;
    int* cb_v  = cb_u + bpad;
    int* gcur_u = cb_v + bpad;
    int* gcur_v = gcur_u + bpad;

    cumsum_w<<<(D_IN * O_OUT + 255) / 256, 256, 0, stream>>>(
        wu, wv, wcu, wcv, wtbu, wtbv);
    zero_i32<<<(2 * (int)bpad + 255) / 256, 256, 0, stream>>>(cnt_u, 2 * (int)bpad);
    coarse_hist<<<512, 256, 0, stream>>>(sup_rows, sup_cols, cnt_u, cnt_v,
                                         nE5, nbu, nbv);
    coarse_scan<<<2, 512, 0, stream>>>(cnt_u, cnt_v, cb_u, cb_v, gcur_u,
                                       gcur_v, nbu, nbv);
    coarse_scatter<<<2 * ((nE5 + CHUNK - 1) / CHUNK), 512, 0, stream>>>(
        sup_rows, sup_cols, sup_vals, gcur_u, gcur_v, mid_u, mid_v, nE5, E,
        nbu, nbv);

    // ---- direction u: z_u = relu(sum_r S_r @ (x_v @ Wv_cum[r])) ----
    gemm5_mfma<<<(NV + 63) / 64, 256, 0, stream>>>(x_v, wtbv, tmp5, strideR, NV);
    spmm_sorted<<<nbu, 512, 0, stream>>>(mid_u, cb_u, tmp5, z_u, NU,
                                         (int)strideR);

    // ---- direction v: z_v = relu(sum_r S_r^T @ (x_u @ Wu_cum[r])) ----
    gemm5_mfma<<<(NU + 63) / 64, 256, 0, stream>>>(x_u, wtbu, tmp5, strideR, NU);
    spmm_sorted<<<nbv, 512, 0, stream>>>(mid_v, cb_v, tmp5, z_v, NV,
                                         (int)strideR);
  } else {
    // ---- fallback: push-atomic path ----
    float* wcu = (float*)d_ws;
    float* wcv = wcu + WDO;
    unsigned short* wtbu = (unsigned short*)(wcv + WDO);
    unsigned short* wtbv = wtbu + WDO;
    float* tmp = (float*)(wtbv + WDO);
    const int n4_out = out_size / 4;
    cumsum_w<<<(D_IN * O_OUT + 255) / 256, 256, 0, stream>>>(
        wu, wv, wcu, wcv, wtbu, wtbv);
    zero_f32<<<1024, 256, 0, stream>>>(out, n4_out);
    const int spmm_blocks = (E * 16 + 255) / 256;
    for (int r = 0; r < R_SUP; ++r) {
      const int* rws = sup_rows + (size_t)r * E;
      const int* cls = sup_cols + (size_t)r * E;
      const float* vls = sup_vals + (size_t)r * E;
      gemm64<<<(NV + 63) / 64, 256, 0, stream>>>(x_v, wcv + r * D_IN * O_OUT, tmp, NV);
      spmm_push<<<spmm_blocks, 256, 0, stream>>>(rws, cls, vls, tmp, z_u, E);
      gemm64<<<(NU + 63) / 64, 256, 0, stream>>>(x_u, wcu + r * D_IN * O_OUT, tmp, NU);
      spmm_push<<<spmm_blocks, 256, 0, stream>>>(cls, rws, vls, tmp, z_v, E);
    }
    relu_f32<<<1024, 256, 0, stream>>>(out, n4_out);
  }
}